// Round 3
// baseline (547.075 us; speedup 1.0000x reference)
//
#include <hip/hip_runtime.h>
#include <hip/hip_bf16.h>
#include <math.h>

// Relational Network fused pipeline for MI355X (gfx950).
// B=32, D=64, K=26, QST=256, G=[512x6, 28], AGG at layer 4.
//
// Round 2 changes vs round 1:
//  - k_fused: removed explicit bnxt prefetch (it blew the 128-reg budget at
//    __launch_bounds__(512,4) -> 288B/thread scratch spill, 341MB fetch +
//    295MB write of pure spill traffic). acc(64)+a(16)+b(16)=96 now fits.
//  - k_pack: coalesced READS + scattered writes (was scattered stride-512
//    reads); W4t/W5t transposes likewise flipped; k_zero merged in.

typedef __attribute__((ext_vector_type(8))) short bf16x8;   // 8 bf16 in 4 VGPRs
typedef __attribute__((ext_vector_type(4))) float f32x4;    // MFMA 16x16 accumulator

__device__ __forceinline__ unsigned short f2bf(float f) {
    union { float f; unsigned u; } x; x.f = f;
    unsigned r = x.u + 0x7fffu + ((x.u >> 16) & 1u);   // RNE
    return (unsigned short)(r >> 16);
}

// ---------------- pack / transpose weights (+ zero S) ----------------
// Wp layout per layer: [nt(32)][s(16)][lane(64)][j(8)] bf16, value = W[n][k],
//   n = nt*16 + (lane&15), k = s*32 + (lane>>4)*8 + j   (MFMA B-fragment order)
// All source reads coalesced; destination writes scattered.
#define NP_WP   786432            // 3 * 512*512
#define NP_W0T  26624             // 512*52
#define NP_W4T  393216            // 512*768
#define NP_W5T  262144            // 512*512
#define NP_S    16384             // 32*512
__global__ void k_pack(const float* __restrict__ W1, const float* __restrict__ W2,
                       const float* __restrict__ W3, const float* __restrict__ W0,
                       const float* __restrict__ W4, const float* __restrict__ W5,
                       unsigned short* __restrict__ Wp,   // [3][262144] bf16
                       float* __restrict__ W0t,           // [52][512] fp32
                       float* __restrict__ W4t,           // [768][512] fp32
                       float* __restrict__ W5t,           // [512][512] fp32
                       float* __restrict__ S)             // [32][512] fp32 (zeroed)
{
    int f = blockIdx.x * 256 + threadIdx.x;
    if (f < NP_WP) {
        int l = f >> 18, r = f & 262143;
        int n = r >> 9, k = r & 511;                    // read W[n*512+k] coalesced
        const float* W = (l == 0) ? W1 : (l == 1) ? W2 : W3;
        float v = W[r];
        int nt = n >> 4, i16 = n & 15;
        int s = k >> 5, q4 = (k >> 3) & 3, j = k & 7;
        int lane = q4 * 16 + i16;
        Wp[(size_t)l * 262144 + (((nt * 16 + s) * 64 + lane) << 3) + j] = f2bf(v);
    } else if (f < NP_WP + NP_W0T) {
        int g = f - NP_WP;
        int o = g / 52, k = g % 52;                     // read W0[g] coalesced
        W0t[k * 512 + o] = W0[g];
    } else if (f < NP_WP + NP_W0T + NP_W4T) {
        int g = f - (NP_WP + NP_W0T);
        int o = g / 768, k = g % 768;                   // read W4[g] coalesced
        W4t[k * 512 + o] = W4[g];
    } else if (f < NP_WP + NP_W0T + NP_W4T + NP_W5T) {
        int g = f - (NP_WP + NP_W0T + NP_W4T);
        int o = g >> 9, k = g & 511;                    // read W5[g] coalesced
        W5t[k * 512 + o] = W5[g];
    } else if (f < NP_WP + NP_W0T + NP_W4T + NP_W5T + NP_S) {
        S[f - (NP_WP + NP_W0T + NP_W4T + NP_W5T)] = 0.f;
    }
}
#define NP_TOTAL (NP_WP + NP_W0T + NP_W4T + NP_W5T + NP_S)   // 1484800 -> 5800 blocks

// ---------------- U/V precompute (layer 0 split) ----------------
__global__ __launch_bounds__(512) void k_uv(
    const float* __restrict__ x, const float* __restrict__ b0,
    const float* __restrict__ W0t,
    float* __restrict__ U, float* __restrict__ V)
{
    int b = blockIdx.x >> 3, qg = blockIdx.x & 7;
    __shared__ float xs[8][26];
    int t = threadIdx.x;
    if (t < 8 * 26) xs[t / 26][t % 26] = x[(b * 64 + qg * 8 + t / 26) * 26 + t % 26];
    __syncthreads();
    int o = t;
    float u[8] = {0,0,0,0,0,0,0,0}, v[8] = {0,0,0,0,0,0,0,0};
    for (int k = 0; k < 26; ++k) {
        float wa = W0t[k * 512 + o];
        float wb = W0t[(26 + k) * 512 + o];
        #pragma unroll
        for (int q = 0; q < 8; ++q) {
            u[q] = fmaf(xs[q][k], wa, u[q]);
            v[q] = fmaf(xs[q][k], wb, v[q]);
        }
    }
    float bb = b0[o];
    #pragma unroll
    for (int q = 0; q < 8; ++q) {
        U[(size_t)((b * 64 + qg * 8 + q)) * 512 + o] = u[q] + bb;  // b0 folded into U
        V[(size_t)((b * 64 + qg * 8 + q)) * 512 + o] = v[q];
    }
}

// ---------------- fused heavy layers 1..3 ----------------
// One block per (b,p): 64 pair-rows. h tile 64x512 bf16 in LDS, XOR-swizzled
// 16B granules: (row,k) at row*512 + ((k>>3)^(row&7))*8 + (k&7).
// 8 waves; wave w computes cols [w*64, w*64+64): acc = 4 (row tiles) x 4 (col tiles).
__global__ __launch_bounds__(512, 4) void k_fused(
    const float* __restrict__ U, const float* __restrict__ V,
    const unsigned short* __restrict__ Wp,
    const float* __restrict__ b1, const float* __restrict__ b2, const float* __restrict__ b3,
    float* __restrict__ S)
{
    __shared__ unsigned short hsm[64 * 512];   // 64 KiB
    int t = threadIdx.x;
    int blk = blockIdx.x;
    int b = blk >> 6, p = blk & 63;

    // ---- stage h0 = relu(U[b,q,:] + V[b,p,:]) into LDS (bf16, swizzled) ----
    const float4* U4 = (const float4*)(U + (size_t)(b * 64) * 512);
    const float4* V4 = (const float4*)(V + (size_t)(b * 64 + p) * 512);
    #pragma unroll
    for (int it = 0; it < 16; ++it) {
        int f = it * 512 + t;
        int q = f >> 7, oq = f & 127;
        float4 uu = U4[q * 128 + oq];
        float4 vv = V4[oq];
        ushort4 pk;
        pk.x = f2bf(fmaxf(uu.x + vv.x, 0.f));
        pk.y = f2bf(fmaxf(uu.y + vv.y, 0.f));
        pk.z = f2bf(fmaxf(uu.z + vv.z, 0.f));
        pk.w = f2bf(fmaxf(uu.w + vv.w, 0.f));
        int g = oq >> 1, hh = oq & 1;
        *(ushort4*)&hsm[q * 512 + ((g ^ (q & 7)) << 3) + hh * 4] = pk;
    }

    int wave = t >> 6, lane = t & 63;
    int i16 = lane & 15, q4 = lane >> 4;

    for (int l = 0; l < 3; ++l) {
        const unsigned short* Wl = Wp + l * 262144;
        const float* bl = (l == 0) ? b1 : (l == 1) ? b2 : b3;
        __syncthreads();   // h ready

        f32x4 acc[4][4];
        #pragma unroll
        for (int mt = 0; mt < 4; ++mt)
            #pragma unroll
            for (int j = 0; j < 4; ++j)
                acc[mt][j] = (f32x4){0.f, 0.f, 0.f, 0.f};

        // B fragments: nt = wave*4 + j; offset ((nt*16+s)*64 + lane)*8 shorts
        const unsigned short* Bb = Wl + (size_t)(wave * 4) * 8192 + lane * 8;

        for (int s = 0; s < 16; ++s) {
            bf16x8 bfr[4];
            #pragma unroll
            for (int j = 0; j < 4; ++j)
                bfr[j] = *(const bf16x8*)(Bb + j * 8192 + s * 512);
            bf16x8 a[4];
            #pragma unroll
            for (int mt = 0; mt < 4; ++mt) {
                int row = mt * 16 + i16;
                int g = (s * 4 + q4) ^ (row & 7);
                a[mt] = *(const bf16x8*)&hsm[row * 512 + g * 8];
            }
            #pragma unroll
            for (int j = 0; j < 4; ++j)
                #pragma unroll
                for (int mt = 0; mt < 4; ++mt)
                    acc[mt][j] = __builtin_amdgcn_mfma_f32_16x16x32_bf16(a[mt], bfr[j], acc[mt][j], 0, 0, 0);
        }
        __syncthreads();   // all reads of h done before overwrite

        if (l < 2) {
            #pragma unroll
            for (int j = 0; j < 4; ++j) {
                int col = (wave * 4 + j) * 16 + i16;
                float bb = bl[col];
                #pragma unroll
                for (int mt = 0; mt < 4; ++mt) {
                    #pragma unroll
                    for (int r = 0; r < 4; ++r) {
                        int row = mt * 16 + q4 * 4 + r;
                        float vv = fmaxf(acc[mt][j][r] + bb, 0.f);
                        int g = (col >> 3) ^ (row & 7);
                        hsm[row * 512 + g * 8 + (col & 7)] = f2bf(vv);
                    }
                }
            }
        } else {
            // layer 3: bias + relu + sum over 64 rows -> atomic partial into S[b][col]
            #pragma unroll
            for (int j = 0; j < 4; ++j) {
                int col = (wave * 4 + j) * 16 + i16;
                float bb = bl[col];
                float sum = 0.f;
                #pragma unroll
                for (int mt = 0; mt < 4; ++mt)
                    #pragma unroll
                    for (int r = 0; r < 4; ++r)
                        sum += fmaxf(acc[mt][j][r] + bb, 0.f);
                sum += __shfl_xor(sum, 16);
                sum += __shfl_xor(sum, 32);
                if (q4 == 0) atomicAdd(&S[b * 512 + col], sum);
            }
        }
    }
}

// ---------------- head: layer 4 (768->512, relu) ----------------
__global__ __launch_bounds__(128) void k_l4(
    const float* __restrict__ S, const float* __restrict__ qst,
    const float* __restrict__ W4t, const float* __restrict__ b4,
    float* __restrict__ h4)
{
    int bi = blockIdx.x;
    int b = bi >> 2, seg = bi & 3;
    __shared__ float z[768];
    int t = threadIdx.x;
    for (int i = t; i < 768; i += 128)
        z[i] = (i < 512) ? S[b * 512 + i] : qst[b * 256 + (i - 512)];
    __syncthreads();
    int col = seg * 128 + t;
    float acc = b4[col];
    for (int k = 0; k < 768; ++k) acc = fmaf(W4t[k * 512 + col], z[k], acc);
    h4[b * 512 + col] = fmaxf(acc, 0.f);
}

// ---------------- head: layer 5 (512->512, relu) ----------------
__global__ __launch_bounds__(128) void k_l5(
    const float* __restrict__ h4, const float* __restrict__ W5t,
    const float* __restrict__ b5, float* __restrict__ h5)
{
    int bi = blockIdx.x;
    int b = bi >> 2, seg = bi & 3;
    __shared__ float z[512];
    int t = threadIdx.x;
    for (int i = t; i < 512; i += 128) z[i] = h4[b * 512 + i];
    __syncthreads();
    int col = seg * 128 + t;
    float acc = b5[col];
    for (int k = 0; k < 512; ++k) acc = fmaf(W5t[k * 512 + col], z[k], acc);
    h5[b * 512 + col] = fmaxf(acc, 0.f);
}

// ---------------- head: layer 6 (512->28) + log_softmax ----------------
__global__ __launch_bounds__(512) void k_l6(
    const float* __restrict__ h5, const float* __restrict__ W6,
    const float* __restrict__ b6, float* __restrict__ out)
{
    int b = blockIdx.x, t = threadIdx.x;
    __shared__ float h[512];
    __shared__ float logits[28];
    __shared__ float red[2];
    h[t] = h5[b * 512 + t];
    __syncthreads();
    int o = t >> 4, c = t & 15;
    if (o < 28) {
        float acc = 0.f;
        for (int k = c; k < 512; k += 16) acc = fmaf(W6[o * 512 + k], h[k], acc);
        acc += __shfl_xor(acc, 1);
        acc += __shfl_xor(acc, 2);
        acc += __shfl_xor(acc, 4);
        acc += __shfl_xor(acc, 8);
        if (c == 0) logits[o] = acc + b6[o];
    }
    __syncthreads();
    if (t == 0) {
        float mx = -1e30f;
        for (int cc = 0; cc < 28; ++cc) mx = fmaxf(mx, logits[cc]);
        float se = 0.f;
        for (int cc = 0; cc < 28; ++cc) se += expf(logits[cc] - mx);
        red[0] = mx; red[1] = logf(se);
    }
    __syncthreads();
    if (t < 28) out[b * 28 + t] = logits[t] - red[0] - red[1];
}

extern "C" void kernel_launch(void* const* d_in, const int* in_sizes, int n_in,
                              void* d_out, int out_size, void* d_ws, size_t ws_size,
                              hipStream_t stream)
{
    const float* x   = (const float*)d_in[0];
    const float* qst = (const float*)d_in[1];
    const float* W0  = (const float*)d_in[2];
    const float* b0  = (const float*)d_in[3];
    const float* W1  = (const float*)d_in[4];
    const float* b1  = (const float*)d_in[5];
    const float* W2  = (const float*)d_in[6];
    const float* b2  = (const float*)d_in[7];
    const float* W3  = (const float*)d_in[8];
    const float* b3  = (const float*)d_in[9];
    const float* W4  = (const float*)d_in[10];
    const float* b4  = (const float*)d_in[11];
    const float* W5  = (const float*)d_in[12];
    const float* b5  = (const float*)d_in[13];
    const float* W6  = (const float*)d_in[14];
    const float* b6  = (const float*)d_in[15];
    float* out = (float*)d_out;

    char* ws = (char*)d_ws;
    float*          Uu  = (float*)(ws);                     // 4 MiB
    float*          Vv  = (float*)(ws + 4194304);           // 4 MiB
    unsigned short* Wp  = (unsigned short*)(ws + 8388608);  // 1.5 MiB
    float*          W0t = (float*)(ws + 9961472);           // 104 KiB
    float*          W4t = (float*)(ws + 10067968);          // 1.5 MiB
    float*          W5t = (float*)(ws + 11640832);          // 1 MiB
    float*          S   = (float*)(ws + 12689408);          // 64 KiB
    float*          h4  = (float*)(ws + 12754944);          // 64 KiB
    float*          h5  = (float*)(ws + 12820480);          // 64 KiB

    k_pack <<<(NP_TOTAL + 255) / 256, 256, 0, stream>>>(W1, W2, W3, W0, W4, W5,
                                                        Wp, W0t, W4t, W5t, S);
    k_uv   <<<256, 512, 0, stream>>>(x, b0, W0t, Uu, Vv);
    k_fused<<<2048, 512, 0, stream>>>(Uu, Vv, Wp, b1, b2, b3, S);
    k_l4   <<<128, 128, 0, stream>>>(S, qst, W4t, b4, h4);
    k_l5   <<<128, 128, 0, stream>>>(h4, W5t, b5, h5);
    k_l6   <<<32, 512, 0, stream>>>(h5, W6, b6, out);
}

// Round 4
// 453.399 us; speedup vs baseline: 1.2066x; 1.2066x over previous
//
#include <hip/hip_runtime.h>
#include <hip/hip_bf16.h>
#include <math.h>

// Relational Network fused pipeline for MI355X (gfx950).
// B=32, D=64, K=26, QST=256, G=[512x6, 28], AGG at layer 4.
//
// Round 3 changes vs round 2:
//  - k_fused: #pragma unroll 1 on the layer loop AND the K(s)-loop. The
//    compiler was fully unrolling both constant-trip loops, hoisting dozens
//    of B-fragment loads -> live set >> 128-reg cap at launch_bounds(512,4)
//    -> ~320 B/thread scratch spill (402MB FETCH / 336MB WRITE observed).
//    Rolled loops keep the live set at ~116 regs: no spill.

typedef __attribute__((ext_vector_type(8))) short bf16x8;   // 8 bf16 in 4 VGPRs
typedef __attribute__((ext_vector_type(4))) float f32x4;    // MFMA 16x16 accumulator

__device__ __forceinline__ unsigned short f2bf(float f) {
    union { float f; unsigned u; } x; x.f = f;
    unsigned r = x.u + 0x7fffu + ((x.u >> 16) & 1u);   // RNE
    return (unsigned short)(r >> 16);
}

// ---------------- pack / transpose weights (+ zero S) ----------------
// Wp layout per layer: [nt(32)][s(16)][lane(64)][j(8)] bf16, value = W[n][k],
//   n = nt*16 + (lane&15), k = s*32 + (lane>>4)*8 + j   (MFMA B-fragment order)
// All source reads coalesced; destination writes scattered.
#define NP_WP   786432            // 3 * 512*512
#define NP_W0T  26624             // 512*52
#define NP_W4T  393216            // 512*768
#define NP_W5T  262144            // 512*512
#define NP_S    16384             // 32*512
__global__ void k_pack(const float* __restrict__ W1, const float* __restrict__ W2,
                       const float* __restrict__ W3, const float* __restrict__ W0,
                       const float* __restrict__ W4, const float* __restrict__ W5,
                       unsigned short* __restrict__ Wp,   // [3][262144] bf16
                       float* __restrict__ W0t,           // [52][512] fp32
                       float* __restrict__ W4t,           // [768][512] fp32
                       float* __restrict__ W5t,           // [512][512] fp32
                       float* __restrict__ S)             // [32][512] fp32 (zeroed)
{
    int f = blockIdx.x * 256 + threadIdx.x;
    if (f < NP_WP) {
        int l = f >> 18, r = f & 262143;
        int n = r >> 9, k = r & 511;                    // read W[n*512+k] coalesced
        const float* W = (l == 0) ? W1 : (l == 1) ? W2 : W3;
        float v = W[r];
        int nt = n >> 4, i16 = n & 15;
        int s = k >> 5, q4 = (k >> 3) & 3, j = k & 7;
        int lane = q4 * 16 + i16;
        Wp[(size_t)l * 262144 + (((nt * 16 + s) * 64 + lane) << 3) + j] = f2bf(v);
    } else if (f < NP_WP + NP_W0T) {
        int g = f - NP_WP;
        int o = g / 52, k = g % 52;                     // read W0[g] coalesced
        W0t[k * 512 + o] = W0[g];
    } else if (f < NP_WP + NP_W0T + NP_W4T) {
        int g = f - (NP_WP + NP_W0T);
        int o = g / 768, k = g % 768;                   // read W4[g] coalesced
        W4t[k * 512 + o] = W4[g];
    } else if (f < NP_WP + NP_W0T + NP_W4T + NP_W5T) {
        int g = f - (NP_WP + NP_W0T + NP_W4T);
        int o = g >> 9, k = g & 511;                    // read W5[g] coalesced
        W5t[k * 512 + o] = W5[g];
    } else if (f < NP_WP + NP_W0T + NP_W4T + NP_W5T + NP_S) {
        S[f - (NP_WP + NP_W0T + NP_W4T + NP_W5T)] = 0.f;
    }
}
#define NP_TOTAL (NP_WP + NP_W0T + NP_W4T + NP_W5T + NP_S)

// ---------------- U/V precompute (layer 0 split) ----------------
__global__ __launch_bounds__(512) void k_uv(
    const float* __restrict__ x, const float* __restrict__ b0,
    const float* __restrict__ W0t,
    float* __restrict__ U, float* __restrict__ V)
{
    int b = blockIdx.x >> 3, qg = blockIdx.x & 7;
    __shared__ float xs[8][26];
    int t = threadIdx.x;
    if (t < 8 * 26) xs[t / 26][t % 26] = x[(b * 64 + qg * 8 + t / 26) * 26 + t % 26];
    __syncthreads();
    int o = t;
    float u[8] = {0,0,0,0,0,0,0,0}, v[8] = {0,0,0,0,0,0,0,0};
    for (int k = 0; k < 26; ++k) {
        float wa = W0t[k * 512 + o];
        float wb = W0t[(26 + k) * 512 + o];
        #pragma unroll
        for (int q = 0; q < 8; ++q) {
            u[q] = fmaf(xs[q][k], wa, u[q]);
            v[q] = fmaf(xs[q][k], wb, v[q]);
        }
    }
    float bb = b0[o];
    #pragma unroll
    for (int q = 0; q < 8; ++q) {
        U[(size_t)((b * 64 + qg * 8 + q)) * 512 + o] = u[q] + bb;  // b0 folded into U
        V[(size_t)((b * 64 + qg * 8 + q)) * 512 + o] = v[q];
    }
}

// ---------------- fused heavy layers 1..3 ----------------
// One block per (b,p): 64 pair-rows. h tile 64x512 bf16 in LDS, XOR-swizzled
// 16B granules: (row,k) at row*512 + ((k>>3)^(row&7))*8 + (k&7).
// 8 waves; wave w computes cols [w*64, w*64+64): acc = 4 (row tiles) x 4 (col tiles).
__global__ __launch_bounds__(512, 4) void k_fused(
    const float* __restrict__ U, const float* __restrict__ V,
    const unsigned short* __restrict__ Wp,
    const float* __restrict__ b1, const float* __restrict__ b2, const float* __restrict__ b3,
    float* __restrict__ S)
{
    __shared__ unsigned short hsm[64 * 512];   // 64 KiB
    int t = threadIdx.x;
    int blk = blockIdx.x;
    int b = blk >> 6, p = blk & 63;

    // ---- stage h0 = relu(U[b,q,:] + V[b,p,:]) into LDS (bf16, swizzled) ----
    const float4* U4 = (const float4*)(U + (size_t)(b * 64) * 512);
    const float4* V4 = (const float4*)(V + (size_t)(b * 64 + p) * 512);
    #pragma unroll 1
    for (int it = 0; it < 16; ++it) {
        int f = it * 512 + t;
        int q = f >> 7, oq = f & 127;
        float4 uu = U4[q * 128 + oq];
        float4 vv = V4[oq];
        ushort4 pk;
        pk.x = f2bf(fmaxf(uu.x + vv.x, 0.f));
        pk.y = f2bf(fmaxf(uu.y + vv.y, 0.f));
        pk.z = f2bf(fmaxf(uu.z + vv.z, 0.f));
        pk.w = f2bf(fmaxf(uu.w + vv.w, 0.f));
        int g = oq >> 1, hh = oq & 1;
        *(ushort4*)&hsm[q * 512 + ((g ^ (q & 7)) << 3) + hh * 4] = pk;
    }

    int wave = t >> 6, lane = t & 63;
    int i16 = lane & 15, q4 = lane >> 4;

    #pragma unroll 1
    for (int l = 0; l < 3; ++l) {
        const unsigned short* Wl = Wp + l * 262144;
        const float* bl = (l == 0) ? b1 : (l == 1) ? b2 : b3;
        __syncthreads();   // h ready

        f32x4 acc[4][4];
        #pragma unroll
        for (int mt = 0; mt < 4; ++mt)
            #pragma unroll
            for (int j = 0; j < 4; ++j)
                acc[mt][j] = (f32x4){0.f, 0.f, 0.f, 0.f};

        // B fragments: nt = wave*4 + j; offset ((nt*16+s)*64 + lane)*8 shorts
        const unsigned short* Bb = Wl + (size_t)(wave * 4) * 8192 + lane * 8;

        #pragma unroll 1
        for (int s = 0; s < 16; ++s) {
            bf16x8 bfr[4];
            #pragma unroll
            for (int j = 0; j < 4; ++j)
                bfr[j] = *(const bf16x8*)(Bb + j * 8192 + s * 512);
            bf16x8 a[4];
            #pragma unroll
            for (int mt = 0; mt < 4; ++mt) {
                int row = mt * 16 + i16;
                int g = (s * 4 + q4) ^ (row & 7);
                a[mt] = *(const bf16x8*)&hsm[row * 512 + g * 8];
            }
            #pragma unroll
            for (int j = 0; j < 4; ++j)
                #pragma unroll
                for (int mt = 0; mt < 4; ++mt)
                    acc[mt][j] = __builtin_amdgcn_mfma_f32_16x16x32_bf16(a[mt], bfr[j], acc[mt][j], 0, 0, 0);
        }
        __syncthreads();   // all reads of h done before overwrite

        if (l < 2) {
            #pragma unroll
            for (int j = 0; j < 4; ++j) {
                int col = (wave * 4 + j) * 16 + i16;
                float bb = bl[col];
                #pragma unroll
                for (int mt = 0; mt < 4; ++mt) {
                    #pragma unroll
                    for (int r = 0; r < 4; ++r) {
                        int row = mt * 16 + q4 * 4 + r;
                        float vv = fmaxf(acc[mt][j][r] + bb, 0.f);
                        int g = (col >> 3) ^ (row & 7);
                        hsm[row * 512 + g * 8 + (col & 7)] = f2bf(vv);
                    }
                }
            }
        } else {
            // layer 3: bias + relu + sum over 64 rows -> atomic partial into S[b][col]
            #pragma unroll
            for (int j = 0; j < 4; ++j) {
                int col = (wave * 4 + j) * 16 + i16;
                float bb = bl[col];
                float sum = 0.f;
                #pragma unroll
                for (int mt = 0; mt < 4; ++mt)
                    #pragma unroll
                    for (int r = 0; r < 4; ++r)
                        sum += fmaxf(acc[mt][j][r] + bb, 0.f);
                sum += __shfl_xor(sum, 16);
                sum += __shfl_xor(sum, 32);
                if (q4 == 0) atomicAdd(&S[b * 512 + col], sum);
            }
        }
    }
}

// ---------------- head: layer 4 (768->512, relu) ----------------
__global__ __launch_bounds__(128) void k_l4(
    const float* __restrict__ S, const float* __restrict__ qst,
    const float* __restrict__ W4t, const float* __restrict__ b4,
    float* __restrict__ h4)
{
    int bi = blockIdx.x;
    int b = bi >> 2, seg = bi & 3;
    __shared__ float z[768];
    int t = threadIdx.x;
    for (int i = t; i < 768; i += 128)
        z[i] = (i < 512) ? S[b * 512 + i] : qst[b * 256 + (i - 512)];
    __syncthreads();
    int col = seg * 128 + t;
    float acc = b4[col];
    for (int k = 0; k < 768; ++k) acc = fmaf(W4t[k * 512 + col], z[k], acc);
    h4[b * 512 + col] = fmaxf(acc, 0.f);
}

// ---------------- head: layer 5 (512->512, relu) ----------------
__global__ __launch_bounds__(128) void k_l5(
    const float* __restrict__ h4, const float* __restrict__ W5t,
    const float* __restrict__ b5, float* __restrict__ h5)
{
    int bi = blockIdx.x;
    int b = bi >> 2, seg = bi & 3;
    __shared__ float z[512];
    int t = threadIdx.x;
    for (int i = t; i < 512; i += 128) z[i] = h4[b * 512 + i];
    __syncthreads();
    int col = seg * 128 + t;
    float acc = b5[col];
    for (int k = 0; k < 512; ++k) acc = fmaf(W5t[k * 512 + col], z[k], acc);
    h5[b * 512 + col] = fmaxf(acc, 0.f);
}

// ---------------- head: layer 6 (512->28) + log_softmax ----------------
__global__ __launch_bounds__(512) void k_l6(
    const float* __restrict__ h5, const float* __restrict__ W6,
    const float* __restrict__ b6, float* __restrict__ out)
{
    int b = blockIdx.x, t = threadIdx.x;
    __shared__ float h[512];
    __shared__ float logits[28];
    __shared__ float red[2];
    h[t] = h5[b * 512 + t];
    __syncthreads();
    int o = t >> 4, c = t & 15;
    if (o < 28) {
        float acc = 0.f;
        for (int k = c; k < 512; k += 16) acc = fmaf(W6[o * 512 + k], h[k], acc);
        acc += __shfl_xor(acc, 1);
        acc += __shfl_xor(acc, 2);
        acc += __shfl_xor(acc, 4);
        acc += __shfl_xor(acc, 8);
        if (c == 0) logits[o] = acc + b6[o];
    }
    __syncthreads();
    if (t == 0) {
        float mx = -1e30f;
        for (int cc = 0; cc < 28; ++cc) mx = fmaxf(mx, logits[cc]);
        float se = 0.f;
        for (int cc = 0; cc < 28; ++cc) se += expf(logits[cc] - mx);
        red[0] = mx; red[1] = logf(se);
    }
    __syncthreads();
    if (t < 28) out[b * 28 + t] = logits[t] - red[0] - red[1];
}

extern "C" void kernel_launch(void* const* d_in, const int* in_sizes, int n_in,
                              void* d_out, int out_size, void* d_ws, size_t ws_size,
                              hipStream_t stream)
{
    const float* x   = (const float*)d_in[0];
    const float* qst = (const float*)d_in[1];
    const float* W0  = (const float*)d_in[2];
    const float* b0  = (const float*)d_in[3];
    const float* W1  = (const float*)d_in[4];
    const float* b1  = (const float*)d_in[5];
    const float* W2  = (const float*)d_in[6];
    const float* b2  = (const float*)d_in[7];
    const float* W3  = (const float*)d_in[8];
    const float* b3  = (const float*)d_in[9];
    const float* W4  = (const float*)d_in[10];
    const float* b4  = (const float*)d_in[11];
    const float* W5  = (const float*)d_in[12];
    const float* b5  = (const float*)d_in[13];
    const float* W6  = (const float*)d_in[14];
    const float* b6  = (const float*)d_in[15];
    float* out = (float*)d_out;

    char* ws = (char*)d_ws;
    float*          Uu  = (float*)(ws);                     // 4 MiB
    float*          Vv  = (float*)(ws + 4194304);           // 4 MiB
    unsigned short* Wp  = (unsigned short*)(ws + 8388608);  // 1.5 MiB
    float*          W0t = (float*)(ws + 9961472);           // 104 KiB
    float*          W4t = (float*)(ws + 10067968);          // 1.5 MiB
    float*          W5t = (float*)(ws + 11640832);          // 1 MiB
    float*          S   = (float*)(ws + 12689408);          // 64 KiB
    float*          h4  = (float*)(ws + 12754944);          // 64 KiB
    float*          h5  = (float*)(ws + 12820480);          // 64 KiB

    k_pack <<<(NP_TOTAL + 255) / 256, 256, 0, stream>>>(W1, W2, W3, W0, W4, W5,
                                                        Wp, W0t, W4t, W5t, S);
    k_uv   <<<256, 512, 0, stream>>>(x, b0, W0t, Uu, Vv);
    k_fused<<<2048, 512, 0, stream>>>(Uu, Vv, Wp, b1, b2, b3, S);
    k_l4   <<<128, 128, 0, stream>>>(S, qst, W4t, b4, h4);
    k_l5   <<<128, 128, 0, stream>>>(h4, W5t, b5, h5);
    k_l6   <<<32, 512, 0, stream>>>(h5, W6, b6, out);
}

// Round 5
// 430.631 us; speedup vs baseline: 1.2704x; 1.0529x over previous
//
#include <hip/hip_runtime.h>
#include <hip/hip_bf16.h>
#include <math.h>

// Relational Network fused pipeline for MI355X (gfx950).
// B=32, D=64, K=26, QST=256, G=[512x6, 28], AGG at layer 4.
//
// Round 5 changes vs round 4:
//  - Wp layout reordered to [wave][s][jj][lane][j] so one wave's 4 B-fragments
//    for a given K-step share ONE per-lane address with byte offsets
//    0/1024/2048/3072 (13-bit immediates) and a +4096B bump per s. A-side
//    ds_read_b128 likewise shares one LDS address with offset:mt*16384.
//    This cuts ~7 address VGPRs -> live set fits the 128-reg unified cap at
//    launch_bounds(512,4): round 4 still spilled ~113 B/thread (116MB WRITE).
//  - l4/l5/l6 merged into one k_tail kernel (launch-gap was ~20us each).

typedef __attribute__((ext_vector_type(8))) short bf16x8;   // 8 bf16 in 4 VGPRs
typedef __attribute__((ext_vector_type(4))) float f32x4;    // MFMA 16x16 accumulator

__device__ __forceinline__ unsigned short f2bf(float f) {
    union { float f; unsigned u; } x; x.f = f;
    unsigned r = x.u + 0x7fffu + ((x.u >> 16) & 1u);   // RNE
    return (unsigned short)(r >> 16);
}

// ---------------- pack / transpose weights (+ zero S) ----------------
// Wp layout per layer: [wave(8)][s(16)][jj(4)][lane(64)][j(8)] bf16,
//   value = W[n][k], n = (wave*4+jj)*16 + (lane&15),
//   k = s*32 + (lane>>4)*8 + j.
// All source reads coalesced; destination writes scattered.
#define NP_WP   786432            // 3 * 512*512
#define NP_W0T  26624             // 512*52
#define NP_W4T  393216            // 512*768
#define NP_W5T  262144            // 512*512
#define NP_S    16384             // 32*512
#define NP_TOTAL (NP_WP + NP_W0T + NP_W4T + NP_W5T + NP_S)
__global__ void k_prep(const float* __restrict__ W1, const float* __restrict__ W2,
                       const float* __restrict__ W3, const float* __restrict__ W0,
                       const float* __restrict__ W4, const float* __restrict__ W5,
                       unsigned short* __restrict__ Wp,   // [3][262144] bf16
                       float* __restrict__ W0t,           // [52][512] fp32
                       float* __restrict__ W4t,           // [768][512] fp32
                       float* __restrict__ W5t,           // [512][512] fp32
                       float* __restrict__ S)             // [32][512] fp32 (zeroed)
{
    int f = blockIdx.x * 256 + threadIdx.x;
    if (f < NP_WP) {
        int l = f >> 18, r = f & 262143;
        int n = r >> 9, k = r & 511;                    // read W[n*512+k] coalesced
        const float* W = (l == 0) ? W1 : (l == 1) ? W2 : W3;
        float v = W[r];
        int wv = n >> 6, jj = (n >> 4) & 3, i16 = n & 15;
        int s = k >> 5, q4 = (k >> 3) & 3, j = k & 7;
        int lane = q4 * 16 + i16;
        // flat = (((wv*16 + s)*4 + jj)*64 + lane)*8 + j
        Wp[(size_t)l * 262144 + ((((wv * 16 + s) * 4 + jj) * 64 + lane) << 3) + j] = f2bf(v);
    } else if (f < NP_WP + NP_W0T) {
        int g = f - NP_WP;
        int o = g / 52, k = g % 52;                     // read W0[g] coalesced
        W0t[k * 512 + o] = W0[g];
    } else if (f < NP_WP + NP_W0T + NP_W4T) {
        int g = f - (NP_WP + NP_W0T);
        int o = g / 768, k = g % 768;                   // read W4[g] coalesced
        W4t[k * 512 + o] = W4[g];
    } else if (f < NP_WP + NP_W0T + NP_W4T + NP_W5T) {
        int g = f - (NP_WP + NP_W0T + NP_W4T);
        int o = g >> 9, k = g & 511;                    // read W5[g] coalesced
        W5t[k * 512 + o] = W5[g];
    } else if (f < NP_TOTAL) {
        S[f - (NP_WP + NP_W0T + NP_W4T + NP_W5T)] = 0.f;
    }
}

// ---------------- U/V precompute (layer 0 split) ----------------
__global__ __launch_bounds__(512) void k_uv(
    const float* __restrict__ x, const float* __restrict__ b0,
    const float* __restrict__ W0t,
    float* __restrict__ U, float* __restrict__ V)
{
    int b = blockIdx.x >> 3, qg = blockIdx.x & 7;
    __shared__ float xs[8][26];
    int t = threadIdx.x;
    if (t < 8 * 26) xs[t / 26][t % 26] = x[(b * 64 + qg * 8 + t / 26) * 26 + t % 26];
    __syncthreads();
    int o = t;
    float u[8] = {0,0,0,0,0,0,0,0}, v[8] = {0,0,0,0,0,0,0,0};
    for (int k = 0; k < 26; ++k) {
        float wa = W0t[k * 512 + o];
        float wb = W0t[(26 + k) * 512 + o];
        #pragma unroll
        for (int q = 0; q < 8; ++q) {
            u[q] = fmaf(xs[q][k], wa, u[q]);
            v[q] = fmaf(xs[q][k], wb, v[q]);
        }
    }
    float bb = b0[o];
    #pragma unroll
    for (int q = 0; q < 8; ++q) {
        U[(size_t)((b * 64 + qg * 8 + q)) * 512 + o] = u[q] + bb;  // b0 folded into U
        V[(size_t)((b * 64 + qg * 8 + q)) * 512 + o] = v[q];
    }
}

// ---------------- fused heavy layers 1..3 ----------------
// One block per (b,p): 64 pair-rows. h tile 64x512 bf16 in LDS, XOR-swizzled
// 16B granules: (row,k) at row*512 + ((k>>3)^(row&7))*8 + (k&7).
// 8 waves; wave w computes cols [w*64, w*64+64): acc = 4 (row tiles) x 4 (col tiles).
__global__ __launch_bounds__(512, 4) void k_fused(
    const float* __restrict__ U, const float* __restrict__ V,
    const unsigned short* __restrict__ Wp,
    const float* __restrict__ b1, const float* __restrict__ b2, const float* __restrict__ b3,
    float* __restrict__ S)
{
    __shared__ unsigned short hsm[64 * 512];   // 64 KiB
    int t = threadIdx.x;
    int blk = blockIdx.x;
    int b = blk >> 6, p = blk & 63;

    // ---- stage h0 = relu(U[b,q,:] + V[b,p,:]) into LDS (bf16, swizzled) ----
    const float4* U4 = (const float4*)(U + (size_t)(b * 64) * 512);
    const float4* V4 = (const float4*)(V + (size_t)(b * 64 + p) * 512);
    #pragma unroll 1
    for (int it = 0; it < 16; ++it) {
        int f = it * 512 + t;
        int q = f >> 7, oq = f & 127;
        float4 uu = U4[q * 128 + oq];
        float4 vv = V4[oq];
        ushort4 pk;
        pk.x = f2bf(fmaxf(uu.x + vv.x, 0.f));
        pk.y = f2bf(fmaxf(uu.y + vv.y, 0.f));
        pk.z = f2bf(fmaxf(uu.z + vv.z, 0.f));
        pk.w = f2bf(fmaxf(uu.w + vv.w, 0.f));
        int g = oq >> 1, hh = oq & 1;
        *(ushort4*)&hsm[q * 512 + ((g ^ (q & 7)) << 3) + hh * 4] = pk;
    }

    int wave = t >> 6, lane = t & 63;
    int i16 = lane & 15, q4 = lane >> 4;

    #pragma unroll 1
    for (int l = 0; l < 3; ++l) {
        const float* bl = (l == 0) ? b1 : (l == 1) ? b2 : b3;
        __syncthreads();   // h ready

        f32x4 acc[4][4];
        #pragma unroll
        for (int mt = 0; mt < 4; ++mt)
            #pragma unroll
            for (int j = 0; j < 4; ++j)
                acc[mt][j] = (f32x4){0.f, 0.f, 0.f, 0.f};

        // B fragments: one shared per-lane address; jj at +512 shorts (1024 B),
        // s at +2048 shorts (4096 B).
        const unsigned short* Bb = Wp + (size_t)l * 262144 + wave * 32768 + lane * 8;
        // A fragments: one shared LDS address; mt at +8192 shorts (16384 B).
        const unsigned short* Ab0 = &hsm[i16 * 512];

        #pragma unroll 1
        for (int s = 0; s < 16; ++s) {
            bf16x8 bfr[4];
            #pragma unroll
            for (int j = 0; j < 4; ++j)
                bfr[j] = *(const bf16x8*)(Bb + s * 2048 + j * 512);
            int g = (s * 4 + q4) ^ (i16 & 7);
            const unsigned short* Ab = Ab0 + g * 8;
            bf16x8 a[4];
            #pragma unroll
            for (int mt = 0; mt < 4; ++mt)
                a[mt] = *(const bf16x8*)(Ab + mt * 8192);
            #pragma unroll
            for (int j = 0; j < 4; ++j)
                #pragma unroll
                for (int mt = 0; mt < 4; ++mt)
                    acc[mt][j] = __builtin_amdgcn_mfma_f32_16x16x32_bf16(a[mt], bfr[j], acc[mt][j], 0, 0, 0);
        }
        __syncthreads();   // all reads of h done before overwrite

        if (l < 2) {
            #pragma unroll
            for (int j = 0; j < 4; ++j) {
                int col = (wave * 4 + j) * 16 + i16;
                float bb = bl[col];
                #pragma unroll
                for (int mt = 0; mt < 4; ++mt) {
                    #pragma unroll
                    for (int r = 0; r < 4; ++r) {
                        int row = mt * 16 + q4 * 4 + r;
                        float vv = fmaxf(acc[mt][j][r] + bb, 0.f);
                        int g = (col >> 3) ^ (row & 7);
                        hsm[row * 512 + g * 8 + (col & 7)] = f2bf(vv);
                    }
                }
            }
        } else {
            // layer 3: bias + relu + sum over 64 rows -> atomic partial into S[b][col]
            #pragma unroll
            for (int j = 0; j < 4; ++j) {
                int col = (wave * 4 + j) * 16 + i16;
                float bb = bl[col];
                float sum = 0.f;
                #pragma unroll
                for (int mt = 0; mt < 4; ++mt)
                    #pragma unroll
                    for (int r = 0; r < 4; ++r)
                        sum += fmaxf(acc[mt][j][r] + bb, 0.f);
                sum += __shfl_xor(sum, 16);
                sum += __shfl_xor(sum, 32);
                if (q4 == 0) atomicAdd(&S[b * 512 + col], sum);
            }
        }
    }
}

// ---------------- tail: layers 4,5,6 + log_softmax (one block per batch) ----
__global__ __launch_bounds__(512) void k_tail(
    const float* __restrict__ S, const float* __restrict__ qst,
    const float* __restrict__ W4t, const float* __restrict__ b4,
    const float* __restrict__ W5t, const float* __restrict__ b5,
    const float* __restrict__ W6, const float* __restrict__ b6,
    float* __restrict__ out)
{
    int b = blockIdx.x, t = threadIdx.x;
    __shared__ float z[768];
    __shared__ float h4[512];
    __shared__ float h5[512];
    __shared__ float logits[28];
    __shared__ float red[2];

    for (int i = t; i < 768; i += 512)
        z[i] = (i < 512) ? S[b * 512 + i] : qst[b * 256 + (i - 512)];
    __syncthreads();
    {   // layer 4: 768 -> 512, relu
        float acc = b4[t];
        for (int k = 0; k < 768; ++k) acc = fmaf(W4t[k * 512 + t], z[k], acc);
        h4[t] = fmaxf(acc, 0.f);
    }
    __syncthreads();
    {   // layer 5: 512 -> 512, relu
        float acc = b5[t];
        for (int k = 0; k < 512; ++k) acc = fmaf(W5t[k * 512 + t], h4[k], acc);
        h5[t] = fmaxf(acc, 0.f);
    }
    __syncthreads();
    {   // layer 6: 512 -> 28 (16 lanes per output)
        int o = t >> 4, c = t & 15;
        if (o < 28) {
            float acc = 0.f;
            for (int k = c; k < 512; k += 16) acc = fmaf(W6[o * 512 + k], h5[k], acc);
            acc += __shfl_xor(acc, 1);
            acc += __shfl_xor(acc, 2);
            acc += __shfl_xor(acc, 4);
            acc += __shfl_xor(acc, 8);
            if (c == 0) logits[o] = acc + b6[o];
        }
    }
    __syncthreads();
    if (t == 0) {
        float mx = -1e30f;
        for (int cc = 0; cc < 28; ++cc) mx = fmaxf(mx, logits[cc]);
        float se = 0.f;
        for (int cc = 0; cc < 28; ++cc) se += expf(logits[cc] - mx);
        red[0] = mx; red[1] = logf(se);
    }
    __syncthreads();
    if (t < 28) out[b * 28 + t] = logits[t] - red[0] - red[1];
}

extern "C" void kernel_launch(void* const* d_in, const int* in_sizes, int n_in,
                              void* d_out, int out_size, void* d_ws, size_t ws_size,
                              hipStream_t stream)
{
    const float* x   = (const float*)d_in[0];
    const float* qst = (const float*)d_in[1];
    const float* W0  = (const float*)d_in[2];
    const float* b0  = (const float*)d_in[3];
    const float* W1  = (const float*)d_in[4];
    const float* b1  = (const float*)d_in[5];
    const float* W2  = (const float*)d_in[6];
    const float* b2  = (const float*)d_in[7];
    const float* W3  = (const float*)d_in[8];
    const float* b3  = (const float*)d_in[9];
    const float* W4  = (const float*)d_in[10];
    const float* b4  = (const float*)d_in[11];
    const float* W5  = (const float*)d_in[12];
    const float* b5  = (const float*)d_in[13];
    const float* W6  = (const float*)d_in[14];
    const float* b6  = (const float*)d_in[15];
    float* out = (float*)d_out;

    char* ws = (char*)d_ws;
    float*          Uu  = (float*)(ws);                     // 4 MiB
    float*          Vv  = (float*)(ws + 4194304);           // 4 MiB
    unsigned short* Wp  = (unsigned short*)(ws + 8388608);  // 1.5 MiB
    float*          W0t = (float*)(ws + 9961472);           // 104 KiB
    float*          W4t = (float*)(ws + 10067968);          // 1.5 MiB
    float*          W5t = (float*)(ws + 11640832);          // 1 MiB
    float*          S   = (float*)(ws + 12689408);          // 64 KiB

    k_prep <<<(NP_TOTAL + 255) / 256, 256, 0, stream>>>(W1, W2, W3, W0, W4, W5,
                                                        Wp, W0t, W4t, W5t, S);
    k_uv   <<<256, 512, 0, stream>>>(x, b0, W0t, Uu, Vv);
    k_fused<<<2048, 512, 0, stream>>>(Uu, Vv, Wp, b1, b2, b3, S);
    k_tail <<<32, 512, 0, stream>>>(S, qst, W4t, b4, W5t, b5, W6, b6, out);
}